// Round 7
// baseline (1143.738 us; speedup 1.0000x reference)
//
#include <hip/hip_runtime.h>
#include <cstdint>
#include <cstddef>

#define B_ 512
#define T_ 2048
#define D_ 64
#define H_ 48
#define C_ 3

#define RECON_FLOATS ((size_t)B_ * T_ * D_)            // 67,108,864 floats (output 0)
#define LOGIT_FLOATS ((size_t)B_ * C_)                 // 1536 floats      (output 1)
#define Z_OFF        (RECON_FLOATS + LOGIT_FLOATS)     // z region         (output 2)
// u stash (f32, 50,331,648 floats) lives at out[0..) inside the recon region; dec overwrites it last.
#define ZSUM_STASH   (RECON_FLOATS - 32768)            // zsum stash, disjoint from u stash

// ---------------- encoder: u[b,t,h] = x row . Wenc^T + (benc+bmem); 1 row/thread (round-4 form) ----------------
__global__ __launch_bounds__(256) void k_enc(
    const float* __restrict__ x, const float* __restrict__ Wenc,
    const float* __restrict__ benc, const float* __restrict__ bmem,
    float* __restrict__ out)
{
    __shared__ float sW[16][48][4];   // sW[d4][h][c] = Wenc[h][4*d4+c] -> wave-uniform broadcast reads
    __shared__ float sb[48];
    const int tid = threadIdx.x;
    for (int idx = tid; idx < 48 * 64; idx += 256) {
        int h = idx >> 6, d = idx & 63;
        sW[d >> 2][h][d & 3] = Wenc[idx];
    }
    if (tid < 48) sb[tid] = benc[tid] + bmem[tid];
    __syncthreads();

    const size_t r = (size_t)blockIdx.x * 256 + tid;   // row (b,t)
    const float* xr = x + r * 64;

    float acc[48];
    #pragma unroll
    for (int h = 0; h < 48; ++h) acc[h] = sb[h];

    #pragma unroll 4
    for (int d4 = 0; d4 < 16; ++d4) {
        const float4 xv = *reinterpret_cast<const float4*>(xr + d4 * 4);
        #pragma unroll
        for (int h = 0; h < 48; ++h) {
            const float4 wv = *reinterpret_cast<const float4*>(sW[d4][h]);
            acc[h] = fmaf(xv.x, wv.x, fmaf(xv.y, wv.y, fmaf(xv.z, wv.z, fmaf(xv.w, wv.w, acc[h]))));
        }
    }

    float4* dst = reinterpret_cast<float4*>(out + r * 48);
    #pragma unroll
    for (int j = 0; j < 12; ++j)
        dst[j] = make_float4(acc[4 * j], acc[4 * j + 1], acc[4 * j + 2], acc[4 * j + 3]);
}

// ---------------- recurrence: 2-step blocked (A, A^2), LDS broadcast, 1 wave/batch ----------------
__global__ __launch_bounds__(64) void k_rec(
    const float* __restrict__ Wmem, float* __restrict__ out)
{
    const int lane = threadIdx.x;
    const int b    = blockIdx.x;
    const int h    = lane < H_ ? lane : 0;

    __shared__ float sA[48][48];      // A = 0.9I + 0.1W
    __shared__ float su[2][32 * 48];  // u tile double buffer
    __shared__ float sms[64];         // ms broadcast buffer

    // stage A into LDS
    for (int idx = lane; idx < 48 * 48; idx += 64) {
        const int i = idx / 48, j = idx - i * 48;
        sA[i][j] = 0.1f * Wmem[idx] + (i == j ? 0.9f : 0.0f);
    }
    __syncthreads();

    // wm = row h of A; wm2 = row h of A^2 (built via uniform-broadcast LDS reads)
    float wm[48];
    #pragma unroll
    for (int j = 0; j < 48; ++j) wm[j] = sA[h][j];

    float wm2[48];
    #pragma unroll
    for (int j = 0; j < 48; ++j) wm2[j] = 0.f;
    #pragma unroll 1
    for (int k = 0; k < 48; ++k) {
        const float ahk = sA[h][k];                 // per-lane read (no dynamic VGPR indexing)
        const float4* row = reinterpret_cast<const float4*>(sA[k]);  // uniform -> broadcast
        #pragma unroll
        for (int j4 = 0; j4 < 12; ++j4) {
            const float4 r = row[j4];
            wm2[4 * j4 + 0] = fmaf(ahk, r.x, wm2[4 * j4 + 0]);
            wm2[4 * j4 + 1] = fmaf(ahk, r.y, wm2[4 * j4 + 1]);
            wm2[4 * j4 + 2] = fmaf(ahk, r.z, wm2[4 * j4 + 2]);
            wm2[4 * j4 + 3] = fmaf(ahk, r.w, wm2[4 * j4 + 3]);
        }
    }

    const float* ub = out + (size_t)b * T_ * 48;          // u stash (f32)
    float*       zb = out + Z_OFF + (size_t)b * T_ * 48;

    float4 p[6];
    {
        const float4* s4 = reinterpret_cast<const float4*>(ub);
        #pragma unroll
        for (int k = 0; k < 6; ++k) p[k] = s4[lane * 6 + k];
        #pragma unroll
        for (int k = 0; k < 6; ++k)
            *reinterpret_cast<float4*>(&su[0][lane * 24 + 4 * k]) = p[k];
    }
    __syncthreads();

    float ms = 0.f, zs = 0.f;
    const float kExp = -0.14426950408889634f;  // -0.1 * log2(e)

    #pragma unroll 1
    for (int tile = 0; tile < T_ / 32; ++tile) {
        const int cur = tile & 1;
        const bool more = (tile + 1) < T_ / 32;
        if (more) {   // next-tile global prefetch (hidden under the 16 pairs)
            const float4* n4 = reinterpret_cast<const float4*>(ub + (size_t)(tile + 1) * 1536);
            #pragma unroll
            for (int k = 0; k < 6; ++k) p[k] = n4[lane * 6 + k];
        }
        float* zrow = zb + (size_t)tile * 1536;

        #pragma unroll 1
        for (int pr = 0; pr < 16; ++pr) {     // 16 pairs = 32 steps
            const float* u1 = &su[cur][pr * 96];
            const float* u2 = u1 + 48;

            sms[lane] = ms;                    // broadcast write (early; consumed ~60 instr later)

            // v = A.u1 + u2  (independent of ms; uniform b128 broadcasts of u1)
            float v0 = 0.f, v1 = 0.f, v2 = 0.f, v3 = 0.f;
            const float4* u14 = reinterpret_cast<const float4*>(u1);
            #pragma unroll
            for (int j4 = 0; j4 < 12; ++j4) {
                const float4 uv = u14[j4];
                v0 = fmaf(uv.x, wm[4 * j4 + 0], v0);
                v1 = fmaf(uv.y, wm[4 * j4 + 1], v1);
                v2 = fmaf(uv.z, wm[4 * j4 + 2], v2);
                v3 = fmaf(uv.w, wm[4 * j4 + 3], v3);
            }
            const float u1h = u1[h];
            const float u2h = u2[h];
            const float vh  = ((v0 + v1) + (v2 + v3)) + u2h;

            // consume ms broadcast: A (for ms1) and A^2 (for ms2) share the loads
            float a0 = 0.f, a1 = 0.f, a2 = 0.f, a3 = 0.f;
            float c0 = 0.f, c1 = 0.f, c2 = 0.f, c3 = 0.f;
            const float4* m4 = reinterpret_cast<const float4*>(sms);
            #pragma unroll
            for (int j4 = 0; j4 < 12; ++j4) {
                const float4 mv = m4[j4];
                a0 = fmaf(mv.x, wm[4 * j4 + 0], a0);
                a1 = fmaf(mv.y, wm[4 * j4 + 1], a1);
                a2 = fmaf(mv.z, wm[4 * j4 + 2], a2);
                a3 = fmaf(mv.w, wm[4 * j4 + 3], a3);
                c0 = fmaf(mv.x, wm2[4 * j4 + 0], c0);
                c1 = fmaf(mv.y, wm2[4 * j4 + 1], c1);
                c2 = fmaf(mv.z, wm2[4 * j4 + 2], c2);
                c3 = fmaf(mv.w, wm2[4 * j4 + 3], c3);
            }
            const float ms1 = ((a0 + a1) + (a2 + a3)) + u1h;   // ms_{t+1} (off critical path)
            ms              = ((c0 + c1) + (c2 + c3)) + vh;     // ms_{t+2} (critical)

            const float z1 = __builtin_amdgcn_rcpf(1.0f + __builtin_amdgcn_exp2f(ms1 * kExp));
            const float z2 = __builtin_amdgcn_rcpf(1.0f + __builtin_amdgcn_exp2f(ms  * kExp));
            if (lane < H_) {
                zrow[(2 * pr) * 48 + lane]     = z1;
                zrow[(2 * pr + 1) * 48 + lane] = z2;
                zs += z1 + z2;
            }
        }

        if (more) {
            #pragma unroll
            for (int k = 0; k < 6; ++k)
                *reinterpret_cast<float4*>(&su[cur ^ 1][lane * 24 + 4 * k]) = p[k];
            __syncthreads();   // single wave: cheap; orders DS writes vs next tile's reads
        }
    }

    if (lane < H_) out[ZSUM_STASH + (size_t)b * 48 + lane] = zs;
}

// ---------------- classifier (before dec overwrites the zsum stash) ----------------
__global__ __launch_bounds__(256) void k_cls(
    const float* __restrict__ Wcls, const float* __restrict__ bcls,
    float* __restrict__ out)
{
    const int g = blockIdx.x * 256 + threadIdx.x;
    if (g >= B_ * C_) return;
    const int b = g / C_, c = g - b * C_;
    const float* zsum = out + ZSUM_STASH + (size_t)b * 48;
    float acc = 0.f;
    #pragma unroll
    for (int hh = 0; hh < 48; ++hh) acc = fmaf(zsum[hh], Wcls[c * 48 + hh], acc);
    out[RECON_FLOATS + g] = acc * (1.0f / (float)T_) + bcls[c];
}

// ---------------- decoder: recon row = z row . Wdec^T + bdec; 1 row/thread (round-4 form) ----------------
__global__ __launch_bounds__(256) void k_dec(
    const float* __restrict__ Wdec, const float* __restrict__ bdec,
    float* __restrict__ out)
{
    __shared__ float sW[12][64][4];   // sW[h4][d][c] = Wdec[d][4*h4+c] -> broadcast reads
    __shared__ float sb[64];
    const int tid = threadIdx.x;
    for (int idx = tid; idx < 64 * 48; idx += 256) {
        int d = idx / 48, hh = idx - d * 48;
        sW[hh >> 2][d][hh & 3] = Wdec[idx];
    }
    if (tid < 64) sb[tid] = bdec[tid];
    __syncthreads();

    const size_t r = (size_t)blockIdx.x * 256 + tid;
    const float* zr = out + Z_OFF + r * 48;
    float zrow[48];
    #pragma unroll
    for (int i = 0; i < 12; ++i)
        *reinterpret_cast<float4*>(&zrow[4 * i]) = *reinterpret_cast<const float4*>(zr + 4 * i);

    float* rr = out + r * 64;
    #pragma unroll 4
    for (int dq = 0; dq < 16; ++dq) {
        float4 o;
        #pragma unroll
        for (int c = 0; c < 4; ++c) {
            const int d = dq * 4 + c;
            float a0 = sb[d], a1 = 0.f, a2 = 0.f, a3 = 0.f;
            #pragma unroll
            for (int h4 = 0; h4 < 12; ++h4) {
                const float4 wv = *reinterpret_cast<const float4*>(sW[h4][d]);
                a0 = fmaf(zrow[4 * h4 + 0], wv.x, a0);
                a1 = fmaf(zrow[4 * h4 + 1], wv.y, a1);
                a2 = fmaf(zrow[4 * h4 + 2], wv.z, a2);
                a3 = fmaf(zrow[4 * h4 + 3], wv.w, a3);
            }
            (&o.x)[c] = (a0 + a1) + (a2 + a3);
        }
        *reinterpret_cast<float4*>(rr + dq * 4) = o;
    }
}

extern "C" void kernel_launch(void* const* d_in, const int* in_sizes, int n_in,
                              void* d_out, int out_size, void* d_ws, size_t ws_size,
                              hipStream_t stream) {
    const float* x    = (const float*)d_in[0];
    const float* Wenc = (const float*)d_in[1];
    const float* benc = (const float*)d_in[2];
    const float* Wmem = (const float*)d_in[3];
    const float* bmem = (const float*)d_in[4];
    const float* Wdec = (const float*)d_in[5];
    const float* bdec = (const float*)d_in[6];
    const float* Wcls = (const float*)d_in[7];
    const float* bcls = (const float*)d_in[8];
    float* out = (float*)d_out;

    const int blocks1 = (B_ * T_) / 256;            // 4096 blocks, 1 row/thread
    k_enc<<<dim3(blocks1), dim3(256), 0, stream>>>(x, Wenc, benc, bmem, out);
    k_rec<<<dim3(B_), dim3(64), 0, stream>>>(Wmem, out);
    k_cls<<<dim3((B_ * C_ + 255) / 256), dim3(256), 0, stream>>>(Wcls, bcls, out);
    k_dec<<<dim3(blocks1), dim3(256), 0, stream>>>(Wdec, bdec, out);
}

// Round 8
// 683.624 us; speedup vs baseline: 1.6731x; 1.6731x over previous
//
#include <hip/hip_runtime.h>
#include <cstdint>
#include <cstddef>

#define B_ 512
#define T_ 2048
#define D_ 64
#define H_ 48
#define C_ 3

#define RECON_FLOATS ((size_t)B_ * T_ * D_)            // 67,108,864 floats (output 0)
#define LOGIT_FLOATS ((size_t)B_ * C_)                 // 1536 floats      (output 1)
#define Z_OFF        (RECON_FLOATS + LOGIT_FLOATS)     // z region         (output 2)
// u stash (f32, 50,331,648 floats) lives at out[0..) inside the recon region; dec overwrites it last.
#define ZSUM_STASH   (RECON_FLOATS - 32768)            // zsum stash, disjoint from u stash

// ---------------- encoder GEMM: U[1M x 48] = X[1M x 64] . Wenc^T + (benc+bmem) ----------------
// block: 128 threads (2 waves), 128 rows. wave tile 64 rows x 48 cols.
// lane = rg*4+cg? -> rg = lane>>2 (16), cg = lane&3 (4). thread tile: 4 rows (rg+16k) x 12 cols.
__global__ __launch_bounds__(128) void k_enc(
    const float* __restrict__ x, const float* __restrict__ Wenc,
    const float* __restrict__ benc, const float* __restrict__ bmem,
    float* __restrict__ out)
{
    __shared__ float sx[128][68];   // stride 68: 16B-aligned rows, banks 4r -> 2-way max
    __shared__ float sw[48][68];    // c-stride 68: per-instr banks 16cg+4i -> 2-way max
    __shared__ float sbe[48];

    const int tid = threadIdx.x;

    // stage Wenc (768 f4) + bias
    {
        const float4* wf4 = reinterpret_cast<const float4*>(Wenc);
        #pragma unroll
        for (int m = 0; m < 6; ++m) {
            const int idx = tid + 128 * m;           // < 768
            const int c = idx >> 4, d4 = idx & 15;
            *reinterpret_cast<float4*>(&sw[c][d4 * 4]) = wf4[idx];
        }
    }
    if (tid < 48) sbe[tid] = benc[tid] + bmem[tid];

    // stage x tile (2048 f4, coalesced)
    {
        const float4* xf4 = reinterpret_cast<const float4*>(x) + (size_t)blockIdx.x * 2048;
        #pragma unroll
        for (int m = 0; m < 16; ++m) {
            const int idx = tid + 128 * m;           // < 2048
            const int row = idx >> 4, d4 = idx & 15;
            *reinterpret_cast<float4*>(&sx[row][d4 * 4]) = xf4[idx];
        }
    }
    __syncthreads();

    const int lane = tid & 63;
    const int wv   = tid >> 6;
    const int rg   = lane >> 2;          // 0..15
    const int cg   = lane & 3;           // 0..3
    const int rowb = wv * 64 + rg;       // + 16k
    const int colb = cg * 12;

    float acc[4][12];
    {
        float bia[12];
        #pragma unroll
        for (int m = 0; m < 3; ++m)
            *reinterpret_cast<float4*>(&bia[4 * m]) = *reinterpret_cast<const float4*>(&sbe[colb + 4 * m]);
        #pragma unroll
        for (int k = 0; k < 4; ++k)
            #pragma unroll
            for (int i = 0; i < 12; ++i) acc[k][i] = bia[i];
    }

    #pragma unroll 2
    for (int d4 = 0; d4 < 16; ++d4) {
        float4 xf[4];
        #pragma unroll
        for (int k = 0; k < 4; ++k)
            xf[k] = *reinterpret_cast<const float4*>(&sx[rowb + 16 * k][d4 * 4]);
        #pragma unroll
        for (int i = 0; i < 12; ++i) {
            const float4 wvv = *reinterpret_cast<const float4*>(&sw[colb + i][d4 * 4]);
            #pragma unroll
            for (int k = 0; k < 4; ++k)
                acc[k][i] = fmaf(xf[k].x, wvv.x, fmaf(xf[k].y, wvv.y,
                             fmaf(xf[k].z, wvv.z, fmaf(xf[k].w, wvv.w, acc[k][i]))));
        }
    }

    const size_t row0 = (size_t)blockIdx.x * 128 + rowb;
    #pragma unroll
    for (int k = 0; k < 4; ++k) {
        float* dst = out + (row0 + 16 * k) * 48 + colb;
        #pragma unroll
        for (int m = 0; m < 3; ++m)
            *reinterpret_cast<float4*>(dst + 4 * m) =
                make_float4(acc[k][4 * m], acc[k][4 * m + 1], acc[k][4 * m + 2], acc[k][4 * m + 3]);
    }
}

// ---------------- recurrence: 1 wave per batch element; rolled step loop (round-6 verbatim) ----------------
__global__ __launch_bounds__(64) void k_rec(
    const float* __restrict__ Wmem, float* __restrict__ out)
{
    const int lane = threadIdx.x;
    const int b    = blockIdx.x;
    const int h    = lane < H_ ? lane : 0;

    float wm[48];
    #pragma unroll
    for (int j = 0; j < 48; ++j) wm[j] = 0.1f * Wmem[h * 48 + j];

    const float* ub = out + (size_t)b * T_ * 48;
    float*       zb = out + Z_OFF + (size_t)b * T_ * 48;

    __shared__ float su[2][32 * 48];

    float4 p[6];
    {
        const float4* s4 = reinterpret_cast<const float4*>(ub);
        #pragma unroll
        for (int k = 0; k < 6; ++k) p[k] = s4[lane * 6 + k];
        #pragma unroll
        for (int k = 0; k < 6; ++k)
            *reinterpret_cast<float4*>(&su[0][lane * 24 + 4 * k]) = p[k];
    }
    __syncthreads();

    float ms = 0.f, zs = 0.f;
    const float kExp = -0.14426950408889634f;  // -0.1 * log2(e)

    #pragma unroll 1
    for (int tile = 0; tile < T_ / 32; ++tile) {
        const int cur = tile & 1;
        const bool more = (tile + 1) < T_ / 32;

        if (more) {
            const float4* n4 = reinterpret_cast<const float4*>(ub + (size_t)(tile + 1) * 32 * 48);
            #pragma unroll
            for (int k = 0; k < 6; ++k) p[k] = n4[lane * 6 + k];
        }

        const float* sut = su[cur];
        float*       zrow = zb + (size_t)tile * 32 * 48;

        #pragma unroll 1
        for (int s = 0; s < 32; ++s) {
            const float uuv = sut[s * 48 + h];
            float a0 = 0.9f * ms;
            float a1 = 0.f, a2 = 0.f, a3 = 0.f, a4 = 0.f, a5 = 0.f, a6 = 0.f, a7 = 0.f;
            #pragma unroll
            for (int g = 0; g < 6; ++g) {
                const int j = 8 * g;
                const float m0 = __int_as_float(__builtin_amdgcn_readlane(__float_as_int(ms), j + 0));
                const float m1 = __int_as_float(__builtin_amdgcn_readlane(__float_as_int(ms), j + 1));
                const float m2 = __int_as_float(__builtin_amdgcn_readlane(__float_as_int(ms), j + 2));
                const float m3 = __int_as_float(__builtin_amdgcn_readlane(__float_as_int(ms), j + 3));
                const float m4 = __int_as_float(__builtin_amdgcn_readlane(__float_as_int(ms), j + 4));
                const float m5 = __int_as_float(__builtin_amdgcn_readlane(__float_as_int(ms), j + 5));
                const float m6 = __int_as_float(__builtin_amdgcn_readlane(__float_as_int(ms), j + 6));
                const float m7 = __int_as_float(__builtin_amdgcn_readlane(__float_as_int(ms), j + 7));
                a0 = fmaf(m0, wm[j + 0], a0);
                a1 = fmaf(m1, wm[j + 1], a1);
                a2 = fmaf(m2, wm[j + 2], a2);
                a3 = fmaf(m3, wm[j + 3], a3);
                a4 = fmaf(m4, wm[j + 4], a4);
                a5 = fmaf(m5, wm[j + 5], a5);
                a6 = fmaf(m6, wm[j + 6], a6);
                a7 = fmaf(m7, wm[j + 7], a7);
            }
            const float dot = ((a0 + a1) + (a2 + a3)) + ((a4 + a5) + (a6 + a7));
            ms = dot + uuv;
            const float e = __builtin_amdgcn_exp2f(ms * kExp);
            const float z = __builtin_amdgcn_rcpf(1.0f + e);
            if (lane < H_) {
                zrow[s * 48 + lane] = z;
                zs += z;
            }
        }

        if (more) {
            #pragma unroll
            for (int k = 0; k < 6; ++k)
                *reinterpret_cast<float4*>(&su[cur ^ 1][lane * 24 + 4 * k]) = p[k];
            __syncthreads();
        }
    }

    if (lane < H_) out[ZSUM_STASH + (size_t)b * 48 + lane] = zs;
}

// ---------------- classifier (before dec overwrites the zsum stash) ----------------
__global__ __launch_bounds__(256) void k_cls(
    const float* __restrict__ Wcls, const float* __restrict__ bcls,
    float* __restrict__ out)
{
    const int g = blockIdx.x * 256 + threadIdx.x;
    if (g >= B_ * C_) return;
    const int b = g / C_, c = g - b * C_;
    const float* zsum = out + ZSUM_STASH + (size_t)b * 48;
    float acc = 0.f;
    #pragma unroll
    for (int hh = 0; hh < 48; ++hh) acc = fmaf(zsum[hh], Wcls[c * 48 + hh], acc);
    out[RECON_FLOATS + g] = acc * (1.0f / (float)T_) + bcls[c];
}

// ---------------- decoder GEMM: R[1M x 64] = Z[1M x 48] . Wdec^T + bdec ----------------
// block: 256 threads (4 waves), 256 rows. wave tile 64 rows x 64 cols.
// rg = lane>>3 (8), cg = lane&7 (8). thread tile: 8 rows (rg+8k) x 8 cols (cg*8..).
// W^T in LDS: swT[h][d] -> rank-1 fragment reads (uniform row, cg-offset cols: 2-way max).
__global__ __launch_bounds__(256) void k_dec(
    const float* __restrict__ Wdec, const float* __restrict__ bdec,
    float* __restrict__ out)
{
    __shared__ float sz[256][52];   // stride 52: 16B-aligned, banks 20rg -> conflict-free
    __shared__ float swT[48][68];   // transposed Wdec
    __shared__ float sbd[64];

    const int tid = threadIdx.x;

    // stage Wdec transposed (3072 scalars)
    #pragma unroll
    for (int m = 0; m < 12; ++m) {
        const int idx = tid + 256 * m;               // < 3072
        const int d = idx / 48, hh = idx - d * 48;
        swT[hh][d] = Wdec[idx];
    }
    if (tid < 64) sbd[tid] = bdec[tid];

    // stage z tile (3072 f4, coalesced reads)
    {
        const float4* zf4 = reinterpret_cast<const float4*>(out + Z_OFF) + (size_t)blockIdx.x * 3072;
        #pragma unroll
        for (int m = 0; m < 12; ++m) {
            const int idx = tid + 256 * m;           // < 3072
            const int row = idx / 12, c4 = idx - row * 12;
            *reinterpret_cast<float4*>(&sz[row][c4 * 4]) = zf4[idx];
        }
    }
    __syncthreads();

    const int lane = tid & 63;
    const int wv   = tid >> 6;
    const int rg   = lane >> 3;          // 0..7
    const int cg   = lane & 7;           // 0..7
    const int rowb = wv * 64 + rg;       // + 8k
    const int colb = cg * 8;

    float acc[8][8];
    {
        float bd[8];
        *reinterpret_cast<float4*>(&bd[0]) = *reinterpret_cast<const float4*>(&sbd[colb]);
        *reinterpret_cast<float4*>(&bd[4]) = *reinterpret_cast<const float4*>(&sbd[colb + 4]);
        #pragma unroll
        for (int k = 0; k < 8; ++k)
            #pragma unroll
            for (int c = 0; c < 8; ++c) acc[k][c] = bd[c];
    }

    #pragma unroll 2
    for (int h4 = 0; h4 < 12; ++h4) {
        float4 zf[8];
        #pragma unroll
        for (int k = 0; k < 8; ++k)
            zf[k] = *reinterpret_cast<const float4*>(&sz[rowb + 8 * k][h4 * 4]);
        #pragma unroll
        for (int j = 0; j < 4; ++j) {
            const float4 w0 = *reinterpret_cast<const float4*>(&swT[h4 * 4 + j][colb]);
            const float4 w1 = *reinterpret_cast<const float4*>(&swT[h4 * 4 + j][colb + 4]);
            #pragma unroll
            for (int k = 0; k < 8; ++k) {
                const float zv = j == 0 ? zf[k].x : (j == 1 ? zf[k].y : (j == 2 ? zf[k].z : zf[k].w));
                acc[k][0] = fmaf(zv, w0.x, acc[k][0]);
                acc[k][1] = fmaf(zv, w0.y, acc[k][1]);
                acc[k][2] = fmaf(zv, w0.z, acc[k][2]);
                acc[k][3] = fmaf(zv, w0.w, acc[k][3]);
                acc[k][4] = fmaf(zv, w1.x, acc[k][4]);
                acc[k][5] = fmaf(zv, w1.y, acc[k][5]);
                acc[k][6] = fmaf(zv, w1.z, acc[k][6]);
                acc[k][7] = fmaf(zv, w1.w, acc[k][7]);
            }
        }
    }

    const size_t row0 = (size_t)blockIdx.x * 256 + rowb;
    #pragma unroll
    for (int k = 0; k < 8; ++k) {
        float* dst = out + (row0 + 8 * k) * 64 + colb;
        *reinterpret_cast<float4*>(dst)     = make_float4(acc[k][0], acc[k][1], acc[k][2], acc[k][3]);
        *reinterpret_cast<float4*>(dst + 4) = make_float4(acc[k][4], acc[k][5], acc[k][6], acc[k][7]);
    }
}

extern "C" void kernel_launch(void* const* d_in, const int* in_sizes, int n_in,
                              void* d_out, int out_size, void* d_ws, size_t ws_size,
                              hipStream_t stream) {
    const float* x    = (const float*)d_in[0];
    const float* Wenc = (const float*)d_in[1];
    const float* benc = (const float*)d_in[2];
    const float* Wmem = (const float*)d_in[3];
    const float* bmem = (const float*)d_in[4];
    const float* Wdec = (const float*)d_in[5];
    const float* bdec = (const float*)d_in[6];
    const float* Wcls = (const float*)d_in[7];
    const float* bcls = (const float*)d_in[8];
    float* out = (float*)d_out;

    k_enc<<<dim3((B_ * T_) / 128), dim3(128), 0, stream>>>(x, Wenc, benc, bmem, out);
    k_rec<<<dim3(B_), dim3(64), 0, stream>>>(Wmem, out);
    k_cls<<<dim3((B_ * C_ + 255) / 256), dim3(256), 0, stream>>>(Wcls, bcls, out);
    k_dec<<<dim3((B_ * T_) / 256), dim3(256), 0, stream>>>(Wdec, bdec, out);
}